// Round 8
// baseline (216.119 us; speedup 1.0000x reference)
//
#include <hip/hip_runtime.h>
#include <math.h>

// ---- NSA hyperparameters (compile-time, matches reference config) ----
constexpr int kT    = 2048;
constexpr int kHQ   = 16;
constexpr int kD    = 128;
constexpr int kKS   = 32;
constexpr int kST   = 16;
constexpr int kBS   = 64;
constexpr int kM    = (kT - kKS) / kST + 1;   // 127 compressed tokens
constexpr int kNB   = (kT + kBS - 1) / kBS;   // 32 selection blocks
constexpr int kTopN = 16;
constexpr int kNInit = 2;
constexpr int kWIN  = 512;
constexpr float kNEG = -1e30f;
constexpr float kScale = 0.08838834764831845f; // 128^-0.5

constexpr int kPad    = 32;
constexpr int kKBRows = kT + kPad; // 2080
constexpr int kVTCols = kT + kPad; // 2080

constexpr int kPSt = 72;    // P slab row stride (fp16)
constexpr int kPL  = 136;   // cmp p_lds row stride (bf16 shorts)
constexpr int kOC  = 36;    // lane stride for [64][32]-ish short arrays (72B: bank-spread)
constexpr int kUW  = 9472;  // per-wave union LDS region bytes: oxS 4608 + oxW 4608 + ml 256

typedef __attribute__((ext_vector_type(8))) short short8;
typedef __attribute__((ext_vector_type(4))) short short4v;
typedef __attribute__((ext_vector_type(8))) _Float16 half8;
typedef __attribute__((ext_vector_type(4))) _Float16 half4v;
typedef __attribute__((ext_vector_type(4))) float floatx4;

// RNE float -> bf16 bits
__device__ inline short f2bf(float x) {
    unsigned u = __float_as_uint(x);
    unsigned r = (u + 0x7fffu + ((u >> 16) & 1u)) >> 16;
    return (short)r;
}
__device__ inline float b2f(short h) {
    return __uint_as_float(((unsigned)(unsigned short)h) << 16);
}

// ---------------------------------------------------------------------
// K1: staging (unchanged from R7).  bf16 K rows + fp16 V^T (swapped-QK
// key permutation col = 4*(w&15)+(w>>4); pad rows skip vt — R3 lesson);
// cmp_k bf16 hi/lo planes + cmp V^T bf16 (same perm over m).
// ---------------------------------------------------------------------
__global__ void k_stage(const float* __restrict__ k, const float* __restrict__ v,
                        short* __restrict__ kb, _Float16* __restrict__ vt,
                        short* __restrict__ cmp_kh, short* __restrict__ cmp_kl,
                        short* __restrict__ cvt) {
    const int bid = blockIdx.x;
    const int d = threadIdx.x;
    if (bid < kKBRows) {
        const int row = bid;
        if (row < kT) {
            const int blk = row >> 6, w = row & 63;
            const int col = blk * kBS + 4 * (w & 15) + (w >> 4);
            kb[row * kD + d] = f2bf(k[(size_t)row * kD + d]);
            vt[(size_t)d * kVTCols + col] = (_Float16)v[(size_t)row * kD + d];
        } else {
            kb[row * kD + d] = 0;   // in-bounds, never read
        }
    } else {
        const int m = bid - kKBRows;        // 0..127 (>=kM = zero pad)
        float sk = 0.f, sv = 0.f;
        if (m < kM) {
            const int base = m * kST;
            #pragma unroll
            for (int i = 0; i < kKS; ++i) {
                sk += k[(size_t)(base + i) * kD + d];
                sv += v[(size_t)(base + i) * kD + d];
            }
            sk *= (1.0f / kKS);
            sv *= (1.0f / kKS);
        }
        const short hi = f2bf(sk);
        cmp_kh[m * kD + d] = hi;
        cmp_kl[m * kD + d] = f2bf(sk - b2f(hi));
        const int pc = (m & 64) + 4 * (m & 15) + ((m & 63) >> 4);
        cvt[d * 128 + pc] = f2bf(sv);
    }
}

// ---------------------------------------------------------------------
// Fused NSA kernel, 2 waves per query (block=128, grid=T, t=2047-bid:
// heavy queries dispatch first = LPT packing).
// wave0: Phase A (cmp-attn + topk, R7-proven) -> selm to LDS -> barrier.
// Both waves: walk the union block list taking alternate entries
//   (wave0 odd, wave1 even — wave1 gets the extra; wave0 paid for A).
//   Per-block body is R7's verbatim with per-wave PS/PW slabs; no
//   barriers in the loop.
// Merge: per-wave (m,l) + bf16 partial O to per-wave LDS regions
//   (self-overlay of dead PS/PW), barrier, log-sum-exp merge; each wave
//   stores half the dims.  Empty partials (m=-1e30,l=0) weight to 0.
// __launch_bounds__(128,1): R5/R6 lesson — any tighter cap spills.
// ---------------------------------------------------------------------
__global__ __launch_bounds__(128, 1) void k_nsa(
        const float* __restrict__ q, const float* __restrict__ cw,
        const short* __restrict__ cmp_kh, const short* __restrict__ cmp_kl,
        const short* __restrict__ cvt, const short* __restrict__ kb,
        const _Float16* __restrict__ vt, float* __restrict__ out) {
    const int tid = threadIdx.x;
    const int wave = tid >> 6;
    const int lane = tid & 63;
    const int l15 = lane & 15;
    const int quad = lane >> 4;
    const int t = kT - 1 - blockIdx.x;   // LPT: heavy first

    __shared__ float sp[kNB];
    __shared__ unsigned selm_s;
    __shared__ short ocst[64 * kOC];                 // ocmp stash (wave0 writes)
    __shared__ __align__(16) char ureg[2 * kUW];     // per-wave overlay regions

    char* const myreg = ureg + wave * kUW;
    _Float16* const PSw = (_Float16*)myreg;                  // Phase B slab
    _Float16* const PWw = (_Float16*)(myreg + 16 * kPSt * 2);

    // ---- q head=l15, scaled, split hi/lo bf16 (both waves) ----
    short8 qh[4], ql[4];
    {
        const float* qp = q + ((size_t)t * kHQ + l15) * kD + quad * 8;
        #pragma unroll
        for (int c = 0; c < 4; ++c) {
            const float4 f0 = *(const float4*)(qp + c * 32);
            const float4 f1 = *(const float4*)(qp + c * 32 + 4);
            const float xs[8] = {f0.x, f0.y, f0.z, f0.w, f1.x, f1.y, f1.z, f1.w};
            #pragma unroll
            for (int j = 0; j < 8; ++j) {
                const float x = xs[j] * kScale;
                const short h = f2bf(x);
                qh[c][j] = h;
                ql[c][j] = f2bf(x - b2f(h));
            }
        }
    }

    const int nvalid = (t >= kKS - 1) ? min(kM, (t - (kKS - 1)) / kST + 1) : 0;
    const int cur = t >> 6;

    // ================= Phase A (wave0 only) =================
    if (wave == 0) {
        short* const p_lds = (short*)ureg;   // wave0 region, dead before Phase B
        floatx4 sacc[8];
        #pragma unroll
        for (int mt = 0; mt < 8; ++mt) {
            sacc[mt] = (floatx4){0, 0, 0, 0};
            const short* ah = cmp_kh + (mt * 16 + l15) * 128 + quad * 8;
            const short* al = cmp_kl + (mt * 16 + l15) * 128 + quad * 8;
            #pragma unroll
            for (int c = 0; c < 4; ++c) {
                const short8 Ah = *(const short8*)(ah + c * 32);
                const short8 Al = *(const short8*)(al + c * 32);
                sacc[mt] = __builtin_amdgcn_mfma_f32_16x16x32_bf16(Ah, qh[c], sacc[mt], 0, 0, 0);
                sacc[mt] = __builtin_amdgcn_mfma_f32_16x16x32_bf16(Ah, ql[c], sacc[mt], 0, 0, 0);
                sacc[mt] = __builtin_amdgcn_mfma_f32_16x16x32_bf16(Al, qh[c], sacc[mt], 0, 0, 0);
            }
        }
        float e[8][4];
        float mx = kNEG;
        #pragma unroll
        for (int mt = 0; mt < 8; ++mt)
            #pragma unroll
            for (int r = 0; r < 4; ++r) {
                const int m = mt * 16 + quad * 4 + r;
                const float s = (m < nvalid) ? sacc[mt][r] : kNEG;
                e[mt][r] = s;
                mx = fmaxf(mx, s);
            }
        mx = fmaxf(mx, __shfl_xor(mx, 16));
        mx = fmaxf(mx, __shfl_xor(mx, 32));
        float sum = 0.f;
        #pragma unroll
        for (int mt = 0; mt < 8; ++mt)
            #pragma unroll
            for (int r = 0; r < 4; ++r) {
                const int m = mt * 16 + quad * 4 + r;
                const float ev = (m < nvalid) ? __expf(e[mt][r] - mx) : 0.f;
                e[mt][r] = ev;
                sum += ev;
            }
        sum += __shfl_xor(sum, 16);
        sum += __shfl_xor(sum, 32);
        const float inv = (nvalid > 0) ? (1.f / sum) : 0.f;

        float Z[8], Y[8];
        #pragma unroll
        for (int mt = 0; mt < 8; ++mt) {
            const float p0 = e[mt][0] * inv, p1 = e[mt][1] * inv;
            const float p2 = e[mt][2] * inv, p3 = e[mt][3] * inv;
            e[mt][0] = p0; e[mt][1] = p1; e[mt][2] = p2; e[mt][3] = p3;
            Z[mt] = p0 + p1 + p2 + 0.5f * p3;
            Y[mt] = p3;
        }
        #pragma unroll
        for (int g = 0; g < 2; ++g)
            #pragma unroll
            for (int r = 0; r < 4; ++r) {
                short4v s4;
                s4[0] = f2bf(e[4 * g + 0][r]); s4[1] = f2bf(e[4 * g + 1][r]);
                s4[2] = f2bf(e[4 * g + 2][r]); s4[3] = f2bf(e[4 * g + 3][r]);
                *(short4v*)&p_lds[l15 * kPL + g * 64 + 16 * quad + 4 * r] = s4;
            }
        #pragma unroll
        for (int mt = 0; mt < 8; ++mt) {
            #pragma unroll
            for (int o = 1; o <= 8; o <<= 1) {
                Z[mt] += __shfl_xor(Z[mt], o, 16);
                Y[mt] += __shfl_xor(Y[mt], o, 16);
            }
        }
        const int srcl = ((quad + 3) & 3) * 16 + l15;
        #pragma unroll
        for (int mt = 0; mt < 8; ++mt) {
            const float up  = __shfl(Y[mt], srcl);
            const float upm = __shfl(Y[(mt + 7) & 7], srcl);
            const float pv = quad ? up : (mt ? upm : 0.f);
            const int b = 4 * mt + quad;
            float x = Z[mt] + 0.5f * pv;
            if (b > cur) x = kNEG;
            if (b < kNInit || b == cur) x = 1e30f;
            if (l15 == 0) sp[b] = x;
        }
        bool selp = false;
        if (lane < kNB) {
            const float xv = sp[lane];
            int rank = 0;
            #pragma unroll
            for (int b2 = 0; b2 < kNB; ++b2) {
                const float y = sp[b2];
                rank += (y > xv || (y == xv && b2 < lane)) ? 1 : 0;
            }
            selp = rank < kTopN;
        }
        const unsigned sm = (unsigned)__ballot(selp);
        if (lane == 0) selm_s = sm;

        // cmp PV -> ocst (bf16, same-lane)
        short8 ap[4];
        #pragma unroll
        for (int c = 0; c < 4; ++c)
            ap[c] = *(const short8*)&p_lds[l15 * kPL + c * 32 + quad * 8];
        #pragma unroll
        for (int nt = 0; nt < 8; ++nt) {
            floatx4 oc = (floatx4){0, 0, 0, 0};
            #pragma unroll
            for (int c = 0; c < 4; ++c) {
                const short8 bv = *(const short8*)(cvt + (size_t)(nt * 16 + l15) * 128 + c * 32 + quad * 8);
                oc = __builtin_amdgcn_mfma_f32_16x16x32_bf16(ap[c], bv, oc, 0, 0, 0);
            }
            short4v s4;
            s4[0] = f2bf(oc[0]); s4[1] = f2bf(oc[1]);
            s4[2] = f2bf(oc[2]); s4[3] = f2bf(oc[3]);
            *(short4v*)&ocst[lane * kOC + nt * 4] = s4;
        }
    }
    __syncthreads();

    // ================= Phase B: both waves, alternate blocks ==========
    const unsigned selm = selm_s;
    const int lob = max(0, (t - (kWIN - 1)) >> 6);
    const unsigned lm = 0xFFFFFFFFu >> (31 - cur);
    const unsigned act = (selm & lm) | (lm & ~((1u << lob) - 1u));

    float mS = kNEG, lS = 0.f, mW = kNEG, lW = 0.f;
    floatx4 osel[8], oswa[8];
    #pragma unroll
    for (int n8 = 0; n8 < 8; ++n8) {
        osel[n8] = (floatx4){0, 0, 0, 0};
        oswa[n8] = (floatx4){0, 0, 0, 0};
    }

    unsigned a = act;
    int bi = 0;
    while (a) {
        const int b = __builtin_ctz(a);
        a &= a - 1u;
        const bool mine = ((bi & 1) != wave);   // wave0: odd, wave1: even
        ++bi;
        if (!mine) continue;
        const bool bsel = (selm >> b) & 1u;
        const bool bswa = b >= lob;

        short8 kreg[4][4];
        {
            const short* kp = kb + (size_t)(b * kBS + l15) * kD + quad * 8;
            #pragma unroll
            for (int kt = 0; kt < 4; ++kt)
                #pragma unroll
                for (int c = 0; c < 4; ++c)
                    kreg[kt][c] = *(const short8*)(kp + kt * 16 * kD + c * 32);
        }
        half8 vreg[8][2];
        {
            const _Float16* vp = vt + (size_t)l15 * kVTCols + b * kBS + quad * 8;
            #pragma unroll
            for (int n8 = 0; n8 < 8; ++n8) {
                vreg[n8][0] = *(const half8*)(vp + (size_t)(n8 * 16) * kVTCols);
                vreg[n8][1] = *(const half8*)(vp + (size_t)(n8 * 16) * kVTCols + 32);
            }
        }

        floatx4 acc[4];
        #pragma unroll
        for (int kt = 0; kt < 4; ++kt) {
            acc[kt] = (floatx4){0, 0, 0, 0};
            #pragma unroll
            for (int c = 0; c < 4; ++c)
                acc[kt] = __builtin_amdgcn_mfma_f32_16x16x32_bf16(kreg[kt][c], qh[c], acc[kt], 0, 0, 0);
        }

        const int kbase = b * kBS + quad * 4;
        float bmS = kNEG, bmW = kNEG;
        #pragma unroll
        for (int kt = 0; kt < 4; ++kt)
            #pragma unroll
            for (int r = 0; r < 4; ++r) {
                const int key = kbase + kt * 16 + r;
                const float s = acc[kt][r];
                const bool ca = key <= t;
                const bool wi = ca && (t - key) < kWIN;
                if (ca) bmS = fmaxf(bmS, s);
                if (wi) bmW = fmaxf(bmW, s);
            }
        bmS = fmaxf(bmS, __shfl_xor(bmS, 16));
        bmS = fmaxf(bmS, __shfl_xor(bmS, 32));
        bmW = fmaxf(bmW, __shfl_xor(bmW, 16));
        bmW = fmaxf(bmW, __shfl_xor(bmW, 32));

        float aS = 1.f, aW = 1.f;
        float mSn = mS, mWn = mW;
        if (bsel) { mSn = fmaxf(mS, bmS); aS = __expf(mS - mSn); }
        if (bswa) { mWn = fmaxf(mW, bmW); aW = __expf(mW - mWn); }

        float sumS = 0.f, sumW = 0.f;
        if (bsel && bswa) {
            const float crv = __expf(mSn - mWn);
            #pragma unroll
            for (int r = 0; r < 4; ++r) {
                half4v hs, hw;
                #pragma unroll
                for (int kt = 0; kt < 4; ++kt) {
                    const int key = kbase + kt * 16 + r;
                    const bool ca = key <= t;
                    const bool wi = ca && (t - key) < kWIN;
                    const float e0 = ca ? __expf(acc[kt][r] - mSn) : 0.f;
                    const float e1 = wi ? e0 * crv : 0.f;
                    sumS += e0; sumW += e1;
                    hs[kt] = (_Float16)e0;
                    hw[kt] = (_Float16)e1;
                }
                *(half4v*)&PSw[l15 * kPSt + 16 * quad + 4 * r] = hs;
                *(half4v*)&PWw[l15 * kPSt + 16 * quad + 4 * r] = hw;
            }
        } else if (bsel) {
            #pragma unroll
            for (int r = 0; r < 4; ++r) {
                half4v hs;
                #pragma unroll
                for (int kt = 0; kt < 4; ++kt) {
                    const int key = kbase + kt * 16 + r;
                    const bool ca = key <= t;
                    const float e0 = ca ? __expf(acc[kt][r] - mSn) : 0.f;
                    sumS += e0;
                    hs[kt] = (_Float16)e0;
                }
                *(half4v*)&PSw[l15 * kPSt + 16 * quad + 4 * r] = hs;
            }
        } else {
            #pragma unroll
            for (int r = 0; r < 4; ++r) {
                half4v hw;
                #pragma unroll
                for (int kt = 0; kt < 4; ++kt) {
                    const int key = kbase + kt * 16 + r;
                    const bool ca = key <= t;
                    const bool wi = ca && (t - key) < kWIN;
                    const float e1 = wi ? __expf(acc[kt][r] - mWn) : 0.f;
                    sumW += e1;
                    hw[kt] = (_Float16)e1;
                }
                *(half4v*)&PWw[l15 * kPSt + 16 * quad + 4 * r] = hw;
            }
        }
        sumS += __shfl_xor(sumS, 16);
        sumS += __shfl_xor(sumS, 32);
        sumW += __shfl_xor(sumW, 16);
        sumW += __shfl_xor(sumW, 32);
        if (bsel) { lS = lS * aS + sumS; mS = mSn; }
        if (bswa) { lW = lW * aW + sumW; mW = mWn; }

        float aSh[4], aWh[4];
        #pragma unroll
        for (int r = 0; r < 4; ++r) {
            aSh[r] = __shfl(aS, quad * 4 + r);
            aWh[r] = __shfl(aW, quad * 4 + r);
        }

        half8 apS0, apS1, apW0, apW1;
        if (bsel) {
            apS0 = *(const half8*)&PSw[l15 * kPSt + quad * 8];
            apS1 = *(const half8*)&PSw[l15 * kPSt + 32 + quad * 8];
        }
        if (bswa) {
            apW0 = *(const half8*)&PWw[l15 * kPSt + quad * 8];
            apW1 = *(const half8*)&PWw[l15 * kPSt + 32 + quad * 8];
        }

        #pragma unroll
        for (int n8 = 0; n8 < 8; ++n8) {
            if (bsel) {
                #pragma unroll
                for (int r = 0; r < 4; ++r) osel[n8][r] *= aSh[r];
                osel[n8] = __builtin_amdgcn_mfma_f32_16x16x32_f16(apS0, vreg[n8][0], osel[n8], 0, 0, 0);
                osel[n8] = __builtin_amdgcn_mfma_f32_16x16x32_f16(apS1, vreg[n8][1], osel[n8], 0, 0, 0);
            }
            if (bswa) {
                #pragma unroll
                for (int r = 0; r < 4; ++r) oswa[n8][r] *= aWh[r];
                oswa[n8] = __builtin_amdgcn_mfma_f32_16x16x32_f16(apW0, vreg[n8][0], oswa[n8], 0, 0, 0);
                oswa[n8] = __builtin_amdgcn_mfma_f32_16x16x32_f16(apW1, vreg[n8][1], oswa[n8], 0, 0, 0);
            }
        }
    }

    // ---- dump partial state to this wave's region (overlays dead PS/PW) ----
    {
        short* const oxSw = (short*)myreg;
        short* const oxWw = (short*)(myreg + 64 * kOC * 2);
        float* const mlw  = (float*)(myreg + 2 * 64 * kOC * 2);
        #pragma unroll
        for (int n8 = 0; n8 < 8; ++n8) {
            short4v s4, w4;
            #pragma unroll
            for (int r = 0; r < 4; ++r) {
                s4[r] = f2bf(osel[n8][r]);
                w4[r] = f2bf(oswa[n8][r]);
            }
            *(short4v*)&oxSw[lane * kOC + n8 * 4] = s4;
            *(short4v*)&oxWw[lane * kOC + n8 * 4] = w4;
        }
        if (quad == 0) *(float4*)&mlw[l15 * 4] = make_float4(mS, lS, mW, lW);
    }
    __syncthreads();

    // ---- merged epilogue: log-sum-exp combine, each wave stores 4 n8 ----
    const short* const oxS0 = (const short*)ureg;
    const short* const oxW0 = (const short*)(ureg + 64 * kOC * 2);
    const float* const ml0  = (const float*)(ureg + 2 * 64 * kOC * 2);
    const short* const oxS1 = (const short*)(ureg + kUW);
    const short* const oxW1 = (const short*)(ureg + kUW + 64 * kOC * 2);
    const float* const ml1  = (const float*)(ureg + kUW + 2 * 64 * kOC * 2);
    const int n8lo = wave * 4;

    #pragma unroll
    for (int r = 0; r < 4; ++r) {
        const int h = quad * 4 + r;
        const float4 a0 = *(const float4*)&ml0[h * 4];   // mS0,lS0,mW0,lW0
        const float4 a1 = *(const float4*)&ml1[h * 4];
        const float mMS = fmaxf(a0.x, a1.x);
        const float c0S = __expf(a0.x - mMS);
        const float c1S = __expf(a1.x - mMS);
        const float liS = 1.f / (a0.y * c0S + a1.y * c1S);
        const float mMW = fmaxf(a0.z, a1.z);
        const float c0W = __expf(a0.z - mMW);
        const float c1W = __expf(a1.z - mMW);
        const float liW = 1.f / (a0.w * c0W + a1.w * c1W);
        const float cwa = cw[((size_t)t * kHQ + h) * 3 + 0];
        const float cwb = cw[((size_t)t * kHQ + h) * 3 + 1];
        const float cwc = cw[((size_t)t * kHQ + h) * 3 + 2];
        const float w0 = 1.f / (1.f + __expf(-cwa));
        const float w1 = 1.f / (1.f + __expf(-cwb));
        const float w2 = 1.f / (1.f + __expf(-cwc));
        float* op = out + ((size_t)t * kHQ + h) * kD + l15;
        #pragma unroll
        for (int i = 0; i < 4; ++i) {
            const int n8 = n8lo + i;
            const int j = n8 * 4 + r;
            const float sM = (b2f(oxS0[lane * kOC + j]) * c0S + b2f(oxS1[lane * kOC + j]) * c1S) * liS;
            const float wM = (b2f(oxW0[lane * kOC + j]) * c0W + b2f(oxW1[lane * kOC + j]) * c1W) * liW;
            const float oc = b2f(ocst[lane * kOC + j]);
            op[n8 * 16] = w0 * oc + w1 * sM + w2 * wM;
        }
    }
}

// ---------------------------------------------------------------------
extern "C" void kernel_launch(void* const* d_in, const int* in_sizes, int n_in,
                              void* d_out, int out_size, void* d_ws, size_t ws_size,
                              hipStream_t stream) {
    const float* q  = (const float*)d_in[0];
    const float* k  = (const float*)d_in[1];
    const float* v  = (const float*)d_in[2];
    const float* cw = (const float*)d_in[3];
    float* out = (float*)d_out;

    short* cmp_kh = (short*)d_ws;                        // 128*128 bf16 hi
    short* cmp_kl = cmp_kh + 128 * kD;                   // 128*128 bf16 lo
    short* cvt    = cmp_kl + 128 * kD;                   // 128*128 bf16 (perm)
    short* kb     = cvt + 128 * 128;                     // kKBRows*kD bf16
    _Float16* vt  = (_Float16*)(kb + (size_t)kKBRows * kD);  // kD*kVTCols fp16

    k_stage<<<dim3(kKBRows + 128), dim3(kD), 0, stream>>>(k, v, kb, vt, cmp_kh, cmp_kl, cvt);
    k_nsa<<<dim3(kT), dim3(128), 0, stream>>>(q, cw, cmp_kh, cmp_kl, cvt, kb, vt, out);
}

// Round 9
// 195.182 us; speedup vs baseline: 1.1073x; 1.1073x over previous
//
#include <hip/hip_runtime.h>
#include <math.h>

// ---- NSA hyperparameters (compile-time, matches reference config) ----
constexpr int kT    = 2048;
constexpr int kHQ   = 16;
constexpr int kD    = 128;
constexpr int kKS   = 32;
constexpr int kST   = 16;
constexpr int kBS   = 64;
constexpr int kM    = (kT - kKS) / kST + 1;   // 127 compressed tokens
constexpr int kNB   = (kT + kBS - 1) / kBS;   // 32 selection blocks
constexpr int kTopN = 16;
constexpr int kNInit = 2;
constexpr int kWIN  = 512;
constexpr float kNEG = -1e30f;
constexpr float kScale = 0.08838834764831845f; // 128^-0.5

constexpr int kPSt = 72;    // P slab row stride (fp16)
constexpr int kOC  = 36;    // lane stride for [64][32]-ish short arrays
constexpr int kUW  = 9472;  // per-wave union LDS region bytes

typedef __attribute__((ext_vector_type(8))) short short8;
typedef __attribute__((ext_vector_type(4))) short short4v;
typedef __attribute__((ext_vector_type(8))) _Float16 half8;
typedef __attribute__((ext_vector_type(4))) _Float16 half4v;
typedef __attribute__((ext_vector_type(4))) float floatx4;

// RNE float -> bf16 bits
__device__ inline short f2bf(float x) {
    unsigned u = __float_as_uint(x);
    unsigned r = (u + 0x7fffu + ((u >> 16) & 1u)) >> 16;
    return (short)r;
}
__device__ inline float b2f(short h) {
    return __uint_as_float(((unsigned)(unsigned short)h) << 16);
}

// ---------------------------------------------------------------------
// K1: FRAGMENT-ORDERED staging (R8 post-mortem: the old row-major
// tables made every Phase-B fragment load 16 scattered 64B segments —
// ~512 L1 requests/block-iter = the TA/L1 request-rate wall).  All
// tables are now stored in exact MFMA fragment order so every kernel
// load is base + lane*16B (one coalesced 1KB burst):
//   kb2 [b][kt*4+c][lane][8]  = bf16 K[b*64+kt*16+(lane&15)][c*32+(lane>>4)*8+j]
//   vt2 [b][n8*2+kc][lane][8] = fp16 V[b*64+w][n8*16+(lane&15)],
//        col = kc*32+(lane>>4)*8+j, w = (col&3)*16 + (col>>2)  (key perm)
//   ck2h/ck2l [(mt*4+c)][lane][8] = bf16 hi/lo cmp_k[mt*16+(lane&15)][c*32+..]
//   cv2 [(nt*4+c)][lane][8]  = bf16 cmpV^T with m-perm folded in
// blocks [0,32): kb2   [32,64): vt2 (LDS transpose)   [64,128): cmp (2 m each)
// ---------------------------------------------------------------------
__global__ __launch_bounds__(256) void k_stage(
        const float* __restrict__ k, const float* __restrict__ v,
        short* __restrict__ kb2, _Float16* __restrict__ vt2,
        short* __restrict__ ck2h, short* __restrict__ ck2l,
        short* __restrict__ cv2) {
    const int bid = blockIdx.x;
    const int tid = threadIdx.x;
    __shared__ _Float16 vls[64 * 132];

    if (bid < 32) {
        const int b = bid;
        #pragma unroll
        for (int p = 0; p < 4; ++p) {
            const int idx = p * 256 + tid;          // 0..1023 = g*64 + lane
            const int g = idx >> 6;                  // kt*4 + c
            const int lane2 = idx & 63;
            const int kt = g >> 2, c = g & 3;
            const int l15v = lane2 & 15, quadv = lane2 >> 4;
            const float* src = k + (size_t)(b * 64 + kt * 16 + l15v) * kD + c * 32 + quadv * 8;
            const float4 f0 = *(const float4*)(src);
            const float4 f1 = *(const float4*)(src + 4);
            short8 s;
            s[0] = f2bf(f0.x); s[1] = f2bf(f0.y); s[2] = f2bf(f0.z); s[3] = f2bf(f0.w);
            s[4] = f2bf(f1.x); s[5] = f2bf(f1.y); s[6] = f2bf(f1.z); s[7] = f2bf(f1.w);
            *(short8*)(kb2 + ((size_t)b * 1024 + idx) * 8) = s;
        }
    } else if (bid < 64) {
        const int b = bid - 32;
        // phase 1: coalesced read of V[64 rows][128 dims] -> LDS fp16
        #pragma unroll
        for (int p = 0; p < 8; ++p) {
            const int idx = p * 256 + tid;   // 2048 float4-slots
            const int r = idx >> 5;
            const int d4 = (idx & 31) * 4;
            const float4 f = *(const float4*)(v + (size_t)(b * 64 + r) * kD + d4);
            _Float16* dst = &vls[r * 132 + d4];
            dst[0] = (_Float16)f.x; dst[1] = (_Float16)f.y;
            dst[2] = (_Float16)f.z; dst[3] = (_Float16)f.w;
        }
        __syncthreads();
        // phase 2: fragment-ordered coalesced write with key perm
        #pragma unroll
        for (int p = 0; p < 4; ++p) {
            const int idx = p * 256 + tid;   // g*64 + lane
            const int g = idx >> 6;          // n8*2 + kc
            const int lane2 = idx & 63;
            const int n8 = g >> 1, kc = g & 1;
            const int l15v = lane2 & 15, quadv = lane2 >> 4;
            half8 h;
            #pragma unroll
            for (int j = 0; j < 8; ++j) {
                const int col = kc * 32 + quadv * 8 + j;
                const int w = (col & 3) * 16 + (col >> 2);
                h[j] = vls[w * 132 + n8 * 16 + l15v];
            }
            *(half8*)(vt2 + ((size_t)b * 1024 + idx) * 8) = h;
        }
    } else {
        const int m = (bid - 64) * 2 + (tid >> 7);   // 0..127
        const int d = tid & 127;
        float sk = 0.f, sv = 0.f;
        if (m < kM) {
            const int base = m * kST;
            #pragma unroll
            for (int i = 0; i < kKS; ++i) {
                sk += k[(size_t)(base + i) * kD + d];
                sv += v[(size_t)(base + i) * kD + d];
            }
            sk *= (1.0f / kKS);
            sv *= (1.0f / kKS);
        }
        const short hi = f2bf(sk);
        const short lo = f2bf(sk - b2f(hi));
        // K planes: frag row m -> (mt,l15m); d -> (c,quadv,j)
        const int mt = m >> 4, l15m = m & 15;
        const int c = d >> 5, quadv = (d >> 3) & 3, j = d & 7;
        const int kdst = ((mt * 4 + c) * 64 + quadv * 16 + l15m) * 8 + j;
        ck2h[kdst] = hi;
        ck2l[kdst] = lo;
        // cmp V^T: value V̄[m][d]; dim d -> (nt,l15d); m -> pc (perm) -> (cp,quadp,jp)
        const int nt = d >> 4, l15d = d & 15;
        const int pc = (m & 64) + 4 * (m & 15) + ((m & 63) >> 4);
        const int cp = pc >> 5, quadp = (pc >> 3) & 3, jp = pc & 7;
        cv2[((nt * 4 + cp) * 64 + quadp * 16 + l15d) * 8 + jp] = f2bf(sv);
    }
}

// ---------------------------------------------------------------------
// Fused NSA kernel, 2 waves per query (block=128, grid=T, t=2047-bid).
// Identical numerics/structure to R8 (proven); ONLY the global load
// addressing changed to the fragment-ordered tables (every load is one
// coalesced lane-contiguous 1KB burst + immediate offsets).
// __launch_bounds__(128,1): R5/R6 lesson — tighter caps spill.
// ---------------------------------------------------------------------
__global__ __launch_bounds__(128, 1) void k_nsa(
        const float* __restrict__ q, const float* __restrict__ cw,
        const short* __restrict__ ck2h, const short* __restrict__ ck2l,
        const short* __restrict__ cv2, const short* __restrict__ kb2,
        const _Float16* __restrict__ vt2, float* __restrict__ out) {
    const int tid = threadIdx.x;
    const int wave = tid >> 6;
    const int lane = tid & 63;
    const int l15 = lane & 15;
    const int quad = lane >> 4;
    const int t = kT - 1 - blockIdx.x;   // LPT: heavy first

    __shared__ float sp[kNB];
    __shared__ unsigned selm_s;
    __shared__ short ocst[64 * kOC];                 // ocmp stash (wave0 writes)
    __shared__ __align__(16) char ureg[2 * kUW];     // per-wave overlay regions

    char* const myreg = ureg + wave * kUW;
    _Float16* const PSw = (_Float16*)myreg;                  // Phase B slab
    _Float16* const PWw = (_Float16*)(myreg + 16 * kPSt * 2);

    // ---- q head=l15, scaled, split hi/lo bf16 (both waves) ----
    short8 qh[4], ql[4];
    {
        const float* qp = q + ((size_t)t * kHQ + l15) * kD + quad * 8;
        #pragma unroll
        for (int c = 0; c < 4; ++c) {
            const float4 f0 = *(const float4*)(qp + c * 32);
            const float4 f1 = *(const float4*)(qp + c * 32 + 4);
            const float xs[8] = {f0.x, f0.y, f0.z, f0.w, f1.x, f1.y, f1.z, f1.w};
            #pragma unroll
            for (int j = 0; j < 8; ++j) {
                const float x = xs[j] * kScale;
                const short h = f2bf(x);
                qh[c][j] = h;
                ql[c][j] = f2bf(x - b2f(h));
            }
        }
    }

    const int nvalid = (t >= kKS - 1) ? min(kM, (t - (kKS - 1)) / kST + 1) : 0;
    const int cur = t >> 6;

    // ================= Phase A (wave0 only) =================
    if (wave == 0) {
        short* const p_lds = (short*)ureg;   // wave0 region, dead before Phase B
        constexpr int kPL = 136;
        floatx4 sacc[8];
        #pragma unroll
        for (int mt = 0; mt < 8; ++mt) {
            sacc[mt] = (floatx4){0, 0, 0, 0};
            #pragma unroll
            for (int c = 0; c < 4; ++c) {
                const short8 Ah = *(const short8*)(ck2h + ((mt * 4 + c) * 64 + lane) * 8);
                const short8 Al = *(const short8*)(ck2l + ((mt * 4 + c) * 64 + lane) * 8);
                sacc[mt] = __builtin_amdgcn_mfma_f32_16x16x32_bf16(Ah, qh[c], sacc[mt], 0, 0, 0);
                sacc[mt] = __builtin_amdgcn_mfma_f32_16x16x32_bf16(Ah, ql[c], sacc[mt], 0, 0, 0);
                sacc[mt] = __builtin_amdgcn_mfma_f32_16x16x32_bf16(Al, qh[c], sacc[mt], 0, 0, 0);
            }
        }
        float e[8][4];
        float mx = kNEG;
        #pragma unroll
        for (int mt = 0; mt < 8; ++mt)
            #pragma unroll
            for (int r = 0; r < 4; ++r) {
                const int m = mt * 16 + quad * 4 + r;
                const float s = (m < nvalid) ? sacc[mt][r] : kNEG;
                e[mt][r] = s;
                mx = fmaxf(mx, s);
            }
        mx = fmaxf(mx, __shfl_xor(mx, 16));
        mx = fmaxf(mx, __shfl_xor(mx, 32));
        float sum = 0.f;
        #pragma unroll
        for (int mt = 0; mt < 8; ++mt)
            #pragma unroll
            for (int r = 0; r < 4; ++r) {
                const int m = mt * 16 + quad * 4 + r;
                const float ev = (m < nvalid) ? __expf(e[mt][r] - mx) : 0.f;
                e[mt][r] = ev;
                sum += ev;
            }
        sum += __shfl_xor(sum, 16);
        sum += __shfl_xor(sum, 32);
        const float inv = (nvalid > 0) ? (1.f / sum) : 0.f;

        float Z[8], Y[8];
        #pragma unroll
        for (int mt = 0; mt < 8; ++mt) {
            const float p0 = e[mt][0] * inv, p1 = e[mt][1] * inv;
            const float p2 = e[mt][2] * inv, p3 = e[mt][3] * inv;
            e[mt][0] = p0; e[mt][1] = p1; e[mt][2] = p2; e[mt][3] = p3;
            Z[mt] = p0 + p1 + p2 + 0.5f * p3;
            Y[mt] = p3;
        }
        #pragma unroll
        for (int g = 0; g < 2; ++g)
            #pragma unroll
            for (int r = 0; r < 4; ++r) {
                short4v s4;
                s4[0] = f2bf(e[4 * g + 0][r]); s4[1] = f2bf(e[4 * g + 1][r]);
                s4[2] = f2bf(e[4 * g + 2][r]); s4[3] = f2bf(e[4 * g + 3][r]);
                *(short4v*)&p_lds[l15 * kPL + g * 64 + 16 * quad + 4 * r] = s4;
            }
        #pragma unroll
        for (int mt = 0; mt < 8; ++mt) {
            #pragma unroll
            for (int o = 1; o <= 8; o <<= 1) {
                Z[mt] += __shfl_xor(Z[mt], o, 16);
                Y[mt] += __shfl_xor(Y[mt], o, 16);
            }
        }
        const int srcl = ((quad + 3) & 3) * 16 + l15;
        #pragma unroll
        for (int mt = 0; mt < 8; ++mt) {
            const float up  = __shfl(Y[mt], srcl);
            const float upm = __shfl(Y[(mt + 7) & 7], srcl);
            const float pv = quad ? up : (mt ? upm : 0.f);
            const int b = 4 * mt + quad;
            float x = Z[mt] + 0.5f * pv;
            if (b > cur) x = kNEG;
            if (b < kNInit || b == cur) x = 1e30f;
            if (l15 == 0) sp[b] = x;
        }
        bool selp = false;
        if (lane < kNB) {
            const float xv = sp[lane];
            int rank = 0;
            #pragma unroll
            for (int b2 = 0; b2 < kNB; ++b2) {
                const float y = sp[b2];
                rank += (y > xv || (y == xv && b2 < lane)) ? 1 : 0;
            }
            selp = rank < kTopN;
        }
        const unsigned sm = (unsigned)__ballot(selp);
        if (lane == 0) selm_s = sm;

        // cmp PV -> ocst (bf16, same-lane)
        short8 ap[4];
        #pragma unroll
        for (int c = 0; c < 4; ++c)
            ap[c] = *(const short8*)&p_lds[l15 * kPL + c * 32 + quad * 8];
        #pragma unroll
        for (int nt = 0; nt < 8; ++nt) {
            floatx4 oc = (floatx4){0, 0, 0, 0};
            #pragma unroll
            for (int c = 0; c < 4; ++c) {
                const short8 bv = *(const short8*)(cv2 + ((nt * 4 + c) * 64 + lane) * 8);
                oc = __builtin_amdgcn_mfma_f32_16x16x32_bf16(ap[c], bv, oc, 0, 0, 0);
            }
            short4v s4;
            s4[0] = f2bf(oc[0]); s4[1] = f2bf(oc[1]);
            s4[2] = f2bf(oc[2]); s4[3] = f2bf(oc[3]);
            *(short4v*)&ocst[lane * kOC + nt * 4] = s4;
        }
    }
    __syncthreads();

    // ================= Phase B: both waves, alternate blocks ==========
    const unsigned selm = selm_s;
    const int lob = max(0, (t - (kWIN - 1)) >> 6);
    const unsigned lm = 0xFFFFFFFFu >> (31 - cur);
    const unsigned act = (selm & lm) | (lm & ~((1u << lob) - 1u));

    float mS = kNEG, lS = 0.f, mW = kNEG, lW = 0.f;
    floatx4 osel[8], oswa[8];
    #pragma unroll
    for (int n8 = 0; n8 < 8; ++n8) {
        osel[n8] = (floatx4){0, 0, 0, 0};
        oswa[n8] = (floatx4){0, 0, 0, 0};
    }

    unsigned a = act;
    int bi = 0;
    while (a) {
        const int b = __builtin_ctz(a);
        a &= a - 1u;
        const bool mine = ((bi & 1) != wave);   // wave0: odd, wave1: even
        ++bi;
        if (!mine) continue;
        const bool bsel = (selm >> b) & 1u;
        const bool bswa = b >= lob;

        // ---- coalesced fragment loads: base + lane*16B + imm ----
        const short* kbb = kb2 + ((size_t)b * 1024 + lane) * 8;
        short8 kreg[4][4];
        #pragma unroll
        for (int kt = 0; kt < 4; ++kt)
            #pragma unroll
            for (int c = 0; c < 4; ++c)
                kreg[kt][c] = *(const short8*)(kbb + (kt * 4 + c) * 512);
        const _Float16* vtb = vt2 + ((size_t)b * 1024 + lane) * 8;
        half8 vreg[8][2];
        #pragma unroll
        for (int n8 = 0; n8 < 8; ++n8) {
            vreg[n8][0] = *(const half8*)(vtb + (n8 * 2 + 0) * 512);
            vreg[n8][1] = *(const half8*)(vtb + (n8 * 2 + 1) * 512);
        }

        floatx4 acc[4];
        #pragma unroll
        for (int kt = 0; kt < 4; ++kt) {
            acc[kt] = (floatx4){0, 0, 0, 0};
            #pragma unroll
            for (int c = 0; c < 4; ++c)
                acc[kt] = __builtin_amdgcn_mfma_f32_16x16x32_bf16(kreg[kt][c], qh[c], acc[kt], 0, 0, 0);
        }

        const int kbase = b * kBS + quad * 4;
        float bmS = kNEG, bmW = kNEG;
        #pragma unroll
        for (int kt = 0; kt < 4; ++kt)
            #pragma unroll
            for (int r = 0; r < 4; ++r) {
                const int key = kbase + kt * 16 + r;
                const float s = acc[kt][r];
                const bool ca = key <= t;
                const bool wi = ca && (t - key) < kWIN;
                if (ca) bmS = fmaxf(bmS, s);
                if (wi) bmW = fmaxf(bmW, s);
            }
        bmS = fmaxf(bmS, __shfl_xor(bmS, 16));
        bmS = fmaxf(bmS, __shfl_xor(bmS, 32));
        bmW = fmaxf(bmW, __shfl_xor(bmW, 16));
        bmW = fmaxf(bmW, __shfl_xor(bmW, 32));

        float aS = 1.f, aW = 1.f;
        float mSn = mS, mWn = mW;
        if (bsel) { mSn = fmaxf(mS, bmS); aS = __expf(mS - mSn); }
        if (bswa) { mWn = fmaxf(mW, bmW); aW = __expf(mW - mWn); }

        float sumS = 0.f, sumW = 0.f;
        if (bsel && bswa) {
            const float crv = __expf(mSn - mWn);
            #pragma unroll
            for (int r = 0; r < 4; ++r) {
                half4v hs, hw;
                #pragma unroll
                for (int kt = 0; kt < 4; ++kt) {
                    const int key = kbase + kt * 16 + r;
                    const bool ca = key <= t;
                    const bool wi = ca && (t - key) < kWIN;
                    const float e0 = ca ? __expf(acc[kt][r] - mSn) : 0.f;
                    const float e1 = wi ? e0 * crv : 0.f;
                    sumS += e0; sumW += e1;
                    hs[kt] = (_Float16)e0;
                    hw[kt] = (_Float16)e1;
                }
                *(half4v*)&PSw[l15 * kPSt + 16 * quad + 4 * r] = hs;
                *(half4v*)&PWw[l15 * kPSt + 16 * quad + 4 * r] = hw;
            }
        } else if (bsel) {
            #pragma unroll
            for (int r = 0; r < 4; ++r) {
                half4v hs;
                #pragma unroll
                for (int kt = 0; kt < 4; ++kt) {
                    const int key = kbase + kt * 16 + r;
                    const bool ca = key <= t;
                    const float e0 = ca ? __expf(acc[kt][r] - mSn) : 0.f;
                    sumS += e0;
                    hs[kt] = (_Float16)e0;
                }
                *(half4v*)&PSw[l15 * kPSt + 16 * quad + 4 * r] = hs;
            }
        } else {
            #pragma unroll
            for (int r = 0; r < 4; ++r) {
                half4v hw;
                #pragma unroll
                for (int kt = 0; kt < 4; ++kt) {
                    const int key = kbase + kt * 16 + r;
                    const bool ca = key <= t;
                    const bool wi = ca && (t - key) < kWIN;
                    const float e1 = wi ? __expf(acc[kt][r] - mWn) : 0.f;
                    sumW += e1;
                    hw[kt] = (_Float16)e1;
                }
                *(half4v*)&PWw[l15 * kPSt + 16 * quad + 4 * r] = hw;
            }
        }
        sumS += __shfl_xor(sumS, 16);
        sumS += __shfl_xor(sumS, 32);
        sumW += __shfl_xor(sumW, 16);
        sumW += __shfl_xor(sumW, 32);
        if (bsel) { lS = lS * aS + sumS; mS = mSn; }
        if (bswa) { lW = lW * aW + sumW; mW = mWn; }

        float aSh[4], aWh[4];
        #pragma unroll
        for (int r = 0; r < 4; ++r) {
            aSh[r] = __shfl(aS, quad * 4 + r);
            aWh[r] = __shfl(aW, quad * 4 + r);
        }

        half8 apS0, apS1, apW0, apW1;
        if (bsel) {
            apS0 = *(const half8*)&PSw[l15 * kPSt + quad * 8];
            apS1 = *(const half8*)&PSw[l15 * kPSt + 32 + quad * 8];
        }
        if (bswa) {
            apW0 = *(const half8*)&PWw[l15 * kPSt + quad * 8];
            apW1 = *(const half8*)&PWw[l15 * kPSt + 32 + quad * 8];
        }

        #pragma unroll
        for (int n8 = 0; n8 < 8; ++n8) {
            if (bsel) {
                #pragma unroll
                for (int r = 0; r < 4; ++r) osel[n8][r] *= aSh[r];
                osel[n8] = __builtin_amdgcn_mfma_f32_16x16x32_f16(apS0, vreg[n8][0], osel[n8], 0, 0, 0);
                osel[n8] = __builtin_amdgcn_mfma_f32_16x16x32_f16(apS1, vreg[n8][1], osel[n8], 0, 0, 0);
            }
            if (bswa) {
                #pragma unroll
                for (int r = 0; r < 4; ++r) oswa[n8][r] *= aWh[r];
                oswa[n8] = __builtin_amdgcn_mfma_f32_16x16x32_f16(apW0, vreg[n8][0], oswa[n8], 0, 0, 0);
                oswa[n8] = __builtin_amdgcn_mfma_f32_16x16x32_f16(apW1, vreg[n8][1], oswa[n8], 0, 0, 0);
            }
        }
    }

    // ---- dump partial state to this wave's region (overlays dead PS/PW) ----
    {
        short* const oxSw = (short*)myreg;
        short* const oxWw = (short*)(myreg + 64 * kOC * 2);
        float* const mlw  = (float*)(myreg + 2 * 64 * kOC * 2);
        #pragma unroll
        for (int n8 = 0; n8 < 8; ++n8) {
            short4v s4, w4;
            #pragma unroll
            for (int r = 0; r < 4; ++r) {
                s4[r] = f2bf(osel[n8][r]);
                w4[r] = f2bf(oswa[n8][r]);
            }
            *(short4v*)&oxSw[lane * kOC + n8 * 4] = s4;
            *(short4v*)&oxWw[lane * kOC + n8 * 4] = w4;
        }
        if (quad == 0) *(float4*)&mlw[l15 * 4] = make_float4(mS, lS, mW, lW);
    }
    __syncthreads();

    // ---- merged epilogue: log-sum-exp combine, each wave stores 4 n8 ----
    const short* const oxS0 = (const short*)ureg;
    const short* const oxW0 = (const short*)(ureg + 64 * kOC * 2);
    const float* const ml0  = (const float*)(ureg + 2 * 64 * kOC * 2);
    const short* const oxS1 = (const short*)(ureg + kUW);
    const short* const oxW1 = (const short*)(ureg + kUW + 64 * kOC * 2);
    const float* const ml1  = (const float*)(ureg + kUW + 2 * 64 * kOC * 2);
    const int n8lo = wave * 4;

    #pragma unroll
    for (int r = 0; r < 4; ++r) {
        const int h = quad * 4 + r;
        const float4 a0 = *(const float4*)&ml0[h * 4];   // mS0,lS0,mW0,lW0
        const float4 a1 = *(const float4*)&ml1[h * 4];
        const float mMS = fmaxf(a0.x, a1.x);
        const float c0S = __expf(a0.x - mMS);
        const float c1S = __expf(a1.x - mMS);
        const float liS = 1.f / (a0.y * c0S + a1.y * c1S);
        const float mMW = fmaxf(a0.z, a1.z);
        const float c0W = __expf(a0.z - mMW);
        const float c1W = __expf(a1.z - mMW);
        const float liW = 1.f / (a0.w * c0W + a1.w * c1W);
        const float cwa = cw[((size_t)t * kHQ + h) * 3 + 0];
        const float cwb = cw[((size_t)t * kHQ + h) * 3 + 1];
        const float cwc = cw[((size_t)t * kHQ + h) * 3 + 2];
        const float w0 = 1.f / (1.f + __expf(-cwa));
        const float w1 = 1.f / (1.f + __expf(-cwb));
        const float w2 = 1.f / (1.f + __expf(-cwc));
        float* op = out + ((size_t)t * kHQ + h) * kD + l15;
        #pragma unroll
        for (int i = 0; i < 4; ++i) {
            const int n8 = n8lo + i;
            const int j = n8 * 4 + r;
            const float sM = (b2f(oxS0[lane * kOC + j]) * c0S + b2f(oxS1[lane * kOC + j]) * c1S) * liS;
            const float wM = (b2f(oxW0[lane * kOC + j]) * c0W + b2f(oxW1[lane * kOC + j]) * c1W) * liW;
            const float oc = b2f(ocst[lane * kOC + j]);
            op[n8 * 16] = w0 * oc + w1 * sM + w2 * wM;
        }
    }
}

// ---------------------------------------------------------------------
extern "C" void kernel_launch(void* const* d_in, const int* in_sizes, int n_in,
                              void* d_out, int out_size, void* d_ws, size_t ws_size,
                              hipStream_t stream) {
    const float* q  = (const float*)d_in[0];
    const float* k  = (const float*)d_in[1];
    const float* v  = (const float*)d_in[2];
    const float* cw = (const float*)d_in[3];
    float* out = (float*)d_out;

    short* kb2    = (short*)d_ws;                         // 32*1024*8 shorts (512 KB)
    _Float16* vt2 = (_Float16*)(kb2 + 32 * 1024 * 8);     // 512 KB
    short* ck2h   = (short*)(vt2 + 32 * 1024 * 8);        // 32 KB
    short* ck2l   = ck2h + 32 * 64 * 8;                   // 32 KB
    short* cv2    = ck2l + 32 * 64 * 8;                   // 32 KB

    k_stage<<<dim3(128), dim3(256), 0, stream>>>(k, v, kb2, vt2, ck2h, ck2l, cv2);
    k_nsa<<<dim3(kT), dim3(128), 0, stream>>>(q, cw, ck2h, ck2l, cv2, kb2, vt2, out);
}